// Round 1
// baseline (341.332 us; speedup 1.0000x reference)
//
#include <hip/hip_runtime.h>

#define NB 2      // batch
#define PP 25     // patch area (5x5)
#define NLVL 6

struct Params {
  const float* x1[NLVL];
  const float* x2[NLVL];
  const float* h[NLVL];
  const float* c[NLVL];
  const float* W[NLVL];
  const float* bias[NLVL];
  float* Wmat[NLVL];   // pooling weight matrices, SZ[l] x 128
  float* D[NLVL];      // correlation dot products, B*S*S*9
  float* pooled[NLVL]; // pooled corr, B*25*S*S
  float* hout[NLVL];
  float* cout[NLVL];
  int C[NLVL];
  int S[NLVL];
};

// ---------------------------------------------------------------------------
// Kernel 1: build the k-fold cascaded avgpool(3,2,1) row-weight matrices.
// Single block. A starts as 128x128 identity; each step halves the row count:
// A'[i] = (A[2i-1] + A[2i] + A[2i+1]) / 3 (zero out of range).
// After step s (s=1..6) the first (128>>s)*128 entries are W for level s-1.
// ---------------------------------------------------------------------------
__global__ __launch_bounds__(256) void winit_kernel(Params pr) {
  __shared__ float A[128 * 128];
  const int tid = threadIdx.x;
  for (int e = tid; e < 128 * 128; e += 256)
    A[e] = ((e >> 7) == (e & 127)) ? 1.0f : 0.0f;
  __syncthreads();
  int cur = 128;
  for (int step = 1; step <= 6; ++step) {
    const int half = cur >> 1;
    const int n = half * 128;
    float buf[32];
#pragma unroll
    for (int j = 0; j < 32; ++j) {
      const int e = tid + j * 256;
      if (e < n) {
        const int i = e >> 7, y = e & 127;
        float v = A[(2 * i) * 128 + y] + A[(2 * i + 1) * 128 + y];
        if (2 * i - 1 >= 0) v += A[(2 * i - 1) * 128 + y];
        buf[j] = v * (1.0f / 3.0f);
      }
    }
    __syncthreads();
#pragma unroll
    for (int j = 0; j < 32; ++j) {
      const int e = tid + j * 256;
      if (e < n) A[e] = buf[j];
    }
    __syncthreads();
    float* dst = pr.Wmat[step - 1];
    for (int e = tid; e < n; e += 256) dst[e] = A[e];
    cur = half;
    __syncthreads();
  }
}

// ---------------------------------------------------------------------------
// Kernel 2: D[b,yb,xb,dy,dx] = sum_c f1[b,c,yb,xb] * f2[b,c,yb+dy,xb+dx]
// (zero when the neighbor block is out of range). Block = (b, yb), threads
// split as (xb, channel-group); LDS reduction over channel groups.
// ---------------------------------------------------------------------------
__global__ __launch_bounds__(256) void dcorr_kernel(Params pr) {
  const int lvl = blockIdx.y;
  const int S = pr.S[lvl];
  const int k = lvl + 1;
  const int lg = 7 - k;          // log2(S)
  const int nb = NB * S;
  if ((int)blockIdx.x >= nb) return;
  const int b = blockIdx.x >> lg;
  const int yb = blockIdx.x & (S - 1);
  const int C = pr.C[lvl];
  const int tid = threadIdx.x;
  const int xb = tid & (S - 1);
  const int cg = tid >> lg;
  const int NG = 256 >> lg;

  const float* p1 = pr.x1[lvl] + ((size_t)(b * C) * S + yb) * S;
  const float* p2base = pr.x2[lvl] + (size_t)(b * C) * S * S;

  float acc[9];
#pragma unroll
  for (int j = 0; j < 9; ++j) acc[j] = 0.f;

  for (int cc = cg; cc < C; cc += NG) {
    const float f1 = p1[(size_t)cc * S * S + xb];
    const float* p2c = p2base + (size_t)cc * S * S;
#pragma unroll
    for (int dy = -1; dy <= 1; ++dy) {
      const int yy = yb + dy;
      const bool yok = (yy >= 0) & (yy < S);
#pragma unroll
      for (int dx = -1; dx <= 1; ++dx) {
        const int xx = xb + dx;
        const bool ok = yok & (xx >= 0) & (xx < S);
        const float v = ok ? p2c[yy * S + xx] : 0.f;
        acc[(dy + 1) * 3 + (dx + 1)] += f1 * v;
      }
    }
  }

  __shared__ float red[256 * 9];
#pragma unroll
  for (int j = 0; j < 9; ++j) red[tid * 9 + j] = acc[j];
  __syncthreads();
  if (cg == 0) {
    for (int g = 1; g < NG; ++g) {
#pragma unroll
      for (int j = 0; j < 9; ++j) acc[j] += red[(tid + g * S) * 9 + j];
    }
    float* Dp = pr.D[lvl] + ((size_t)(b * S + yb) * S + xb) * 9;
#pragma unroll
    for (int j = 0; j < 9; ++j) Dp[j] = acc[j];
  }
}

// ---------------------------------------------------------------------------
// Kernel 3: pooled[b,p] = W_k * lrelu(corr(b,p)) * W_k^T  (separable gather).
// corr(b,p,y,x) = D[b, y>>k, x>>k, dy(y%f,pi), dx(x%f,pj)]; block = (b,p).
// ---------------------------------------------------------------------------
__global__ __launch_bounds__(256) void pool_kernel(Params pr) {
  const int lvl = blockIdx.y;
  const int S = pr.S[lvl];
  const int k = lvl + 1;
  const int f = 1 << k;
  const int bp = blockIdx.x;           // 0..49
  const int b = bp / PP;
  const int p = bp % PP;
  const int dpy = p / 5 - 2;
  const int dpx = p % 5 - 2;
  const float* Wm = pr.Wmat[lvl];
  const float* Dp = pr.D[lvl] + (size_t)b * S * S * 9;
  __shared__ float tmp[64 * 128];
  const int tid = threadIdx.x;

  // phase 1: contract over y  -> tmp[yo][x], x at full 128 resolution
  for (int item = tid; item < S * 128; item += 256) {
    const int yo = item >> 7;
    const int x = item & 127;
    const int xb = x >> k;
    const int tx = x & (f - 1);
    const int dxi = (tx + dpx < 0) ? 0 : ((tx + dpx >= f) ? 2 : 1);
    int lo = yo * f - (f - 1); if (lo < 0) lo = 0;
    int hi = yo * f + (f - 1); if (hi > 127) hi = 127;
    float sum = 0.f;
    for (int y = lo; y <= hi; ++y) {
      const float w = Wm[yo * 128 + y];
      const int yb = y >> k;
      const int ty = y & (f - 1);
      const int dyi = (ty + dpy < 0) ? 0 : ((ty + dpy >= f) ? 2 : 1);
      float v = Dp[((size_t)yb * S + xb) * 9 + dyi * 3 + dxi];
      v = (v > 0.f) ? v : 0.01f * v;          // leaky relu
      sum += w * v;
    }
    tmp[item] = sum;
  }
  __syncthreads();

  // phase 2: contract over x -> pooled[yo][xo]
  float* out = pr.pooled[lvl] + (size_t)(b * PP + p) * S * S;
  for (int item = tid; item < S * S; item += 256) {
    const int yo = item / S;
    const int xo = item - yo * S;
    int lo = xo * f - (f - 1); if (lo < 0) lo = 0;
    int hi = xo * f + (f - 1); if (hi > 127) hi = 127;
    float sum = 0.f;
    for (int x = lo; x <= hi; ++x)
      sum += Wm[xo * 128 + x] * tmp[yo * 128 + x];
    out[item] = sum;
  }
}

// ---------------------------------------------------------------------------
// Kernel 4: 3x3 conv (50 -> 100 ch) over [pooled corr ; h_pre] + LSTM gating.
// Block = (b, y). Stages 3 input rows x 50 ch in LDS; each thread owns one p
// and an 8-wide x chunk, computing all 4 gates (i,f,o,g) so the LSTM can be
// applied without materializing gates.
// ---------------------------------------------------------------------------
__global__ __launch_bounds__(256) void gate_kernel(Params pr) {
  const int lvl = blockIdx.y;
  const int S = pr.S[lvl];
  const int k = lvl + 1;
  const int lg = 7 - k;
  const int nb = NB * S;
  if ((int)blockIdx.x >= nb) return;
  const int b = blockIdx.x >> lg;
  const int y = blockIdx.x & (S - 1);

  const float* pooled = pr.pooled[lvl] + (size_t)b * PP * S * S;
  const float* hin = pr.h[lvl] + (size_t)b * PP * S * S;
  const float* cin = pr.c[lvl] + (size_t)b * PP * S * S;
  const float* Wt = pr.W[lvl];
  const float* bias = pr.bias[lvl];

  __shared__ float lds[3 * 50 * 64];
  const int tid = threadIdx.x;
  for (int ky = 0; ky < 3; ++ky) {
    const int yy = y + ky - 1;
    const bool yok = (yy >= 0) && (yy < S);
    for (int idx = tid; idx < 50 * S; idx += 256) {
      const int ic = idx >> lg;
      const int x = idx & (S - 1);
      float v = 0.f;
      if (yok)
        v = (ic < PP) ? pooled[((size_t)ic * S + yy) * S + x]
                      : hin[((size_t)(ic - PP) * S + yy) * S + x];
      lds[(ky * 50 + ic) * 64 + x] = v;
    }
  }
  __syncthreads();

  const int XC = (S >= 8) ? 8 : S;          // x chunk per thread
  const int nxc = S / XC;
  const int nitems = PP * nxc;              // <= 200
  if (tid >= nitems) return;
  const int p = tid / nxc;
  const int x0 = (tid - p * nxc) * XC;

  float acc[4][8];
#pragma unroll
  for (int q = 0; q < 4; ++q)
#pragma unroll
    for (int xx = 0; xx < 8; ++xx) acc[q][xx] = 0.f;

  for (int ic = 0; ic < 50; ++ic) {
#pragma unroll
    for (int ky = 0; ky < 3; ++ky) {
      float seg[10];
      const float* lrow = &lds[(ky * 50 + ic) * 64];
#pragma unroll
      for (int t = 0; t < 10; ++t) {
        const int x = x0 - 1 + t;
        seg[t] = (x >= 0 && x < S && t < XC + 2) ? lrow[x] : 0.f;
      }
#pragma unroll
      for (int q = 0; q < 4; ++q) {
        const int oc = p + q * PP;
        const float* wp = Wt + ((size_t)(oc * 50 + ic) * 3 + ky) * 3;
        const float w0 = wp[0], w1 = wp[1], w2 = wp[2];
#pragma unroll
        for (int xx = 0; xx < 8; ++xx)
          acc[q][xx] += w0 * seg[xx] + w1 * seg[xx + 1] + w2 * seg[xx + 2];
      }
    }
  }

  const float bi = bias[p], bf = bias[p + 25], bo = bias[p + 50], bg = bias[p + 75];
  float* ho = pr.hout[lvl];
  float* co = pr.cout[lvl];
  for (int xx = 0; xx < XC; ++xx) {
    const int x = x0 + xx;
    const float gi = acc[0][xx] + bi;
    const float gf = acc[1][xx] + bf;
    const float go = acc[2][xx] + bo;
    const float gg = acc[3][xx] + bg;
    const float i_ = 1.f / (1.f + __expf(-gi));
    const float f_ = 1.f / (1.f + __expf(-gf));
    const float o_ = 1.f / (1.f + __expf(-go));
    const float g_ = 1.f - 2.f / (__expf(2.f * gg) + 1.f);   // tanh
    const float cp = cin[((size_t)p * S + y) * S + x];
    const float cn = f_ * cp + i_ * g_;
    const float t2 = 1.f - 2.f / (__expf(2.f * cn) + 1.f);   // tanh
    const float hn = o_ * t2;
    const size_t oidx = ((size_t)(b * PP + p) * S + y) * S + x;
    ho[oidx] = hn;
    co[oidx] = cn;
  }
}

// ---------------------------------------------------------------------------
extern "C" void kernel_launch(void* const* d_in, const int* in_sizes, int n_in,
                              void* d_out, int out_size, void* d_ws, size_t ws_size,
                              hipStream_t stream) {
  static const int CH[NLVL] = {512, 1024, 512, 256, 256, 256};
  static const int SZ[NLVL] = {64, 32, 16, 8, 4, 2};

  Params pr;
  float* ws = (float*)d_ws;
  size_t off = 0;
  for (int l = 0; l < NLVL; ++l) { pr.Wmat[l] = ws + off; off += (size_t)SZ[l] * 128; }
  for (int l = 0; l < NLVL; ++l) { pr.D[l] = ws + off; off += (size_t)NB * SZ[l] * SZ[l] * 9; }
  for (int l = 0; l < NLVL; ++l) { pr.pooled[l] = ws + off; off += (size_t)NB * PP * SZ[l] * SZ[l]; }

  float* out = (float*)d_out;
  size_t ooff = 0;
  for (int l = 0; l < NLVL; ++l) {
    pr.hout[l] = out + ooff; ooff += (size_t)NB * PP * SZ[l] * SZ[l];
    pr.cout[l] = out + ooff; ooff += (size_t)NB * PP * SZ[l] * SZ[l];
  }

  for (int l = 0; l < NLVL; ++l) {
    pr.x1[l] = (const float*)d_in[4 * l + 0];
    pr.x2[l] = (const float*)d_in[4 * l + 1];
    pr.h[l]  = (const float*)d_in[4 * l + 2];
    pr.c[l]  = (const float*)d_in[4 * l + 3];
    pr.W[l]   = (const float*)d_in[24 + 2 * l];
    pr.bias[l] = (const float*)d_in[25 + 2 * l];
    pr.C[l] = CH[l];
    pr.S[l] = SZ[l];
  }

  winit_kernel<<<dim3(1), 256, 0, stream>>>(pr);
  dcorr_kernel<<<dim3(NB * 64, NLVL), 256, 0, stream>>>(pr);
  pool_kernel<<<dim3(NB * PP, NLVL), 256, 0, stream>>>(pr);
  gate_kernel<<<dim3(NB * 64, NLVL), 256, 0, stream>>>(pr);
}

// Round 2
// 307.122 us; speedup vs baseline: 1.1114x; 1.1114x over previous
//
#include <hip/hip_runtime.h>

#define NB 2      // batch
#define PP 25     // patch area (5x5)
#define NLVL 6

struct Params {
  const float* x1[NLVL];
  const float* x2[NLVL];
  const float* h[NLVL];
  const float* c[NLVL];
  const float* W[NLVL];
  const float* bias[NLVL];
  float* D[NLVL];       // correlation dot products, B*S*S*9  (atomically accumulated)
  float* pooled[NLVL];  // pooled corr, B*25*S*S
  float* WT[NLVL];      // repacked weights [(ic*9+t)*100 + oc]
  float* gates[NLVL];   // conv outputs, 4*NB*25*S*S
  float* hout[NLVL];
  float* cout[NLVL];
};

__device__ __forceinline__ float lrelu(float v) { return v > 0.f ? v : 0.01f * v; }

// ---------------------------------------------------------------------------
// Repack W[oc][ic][ky][kx] -> WT[(ic*9+t)][oc] so a wave's weight load is
// 25 consecutive floats (lane = p) instead of 8 cache lines 1800B apart.
// ---------------------------------------------------------------------------
__global__ __launch_bounds__(256) void repack_kernel(Params pr) {
  const int lvl = blockIdx.y;
  const float* W = pr.W[lvl];
  float* WT = pr.WT[lvl];
  for (int i = blockIdx.x * 256 + threadIdx.x; i < 100 * 450; i += gridDim.x * 256) {
    const int oc = i / 450;
    const int r = i - oc * 450;   // r = ic*9 + (ky*3+kx)
    WT[r * 100 + oc] = W[i];
  }
}

// ---------------------------------------------------------------------------
// dcorr: D[b,yb,xb,dy,dx] += sum_{c in chunk} f1[b,c,yb,xb]*f2[b,c,yb+dy,xb+dx]
// block = (row=(b,yb), channel-chunk); LDS tree-reduce over channel groups,
// then 9 atomic adds per site. D must be pre-zeroed (hipMemsetAsync).
// ---------------------------------------------------------------------------
__global__ __launch_bounds__(256) void dcorr_kernel(Params pr) {
  static const int SZt[6] = {64, 32, 16, 8, 4, 2};
  static const int CHt[6] = {512, 1024, 512, 256, 256, 256};
  static const int NCH[6] = {16, 32, 8, 4, 2, 1};
  static const int LG[6]  = {6, 5, 4, 3, 2, 1};
  const int lvl = blockIdx.y;
  const int S = SZt[lvl], C = CHt[lvl], nch = NCH[lvl], lg = LG[lvl];
  const int rows = NB * S;
  const int bid = blockIdx.x;
  if (bid >= rows * nch) return;
  const int row = bid / nch;
  const int chunk = bid - row * nch;
  const int b = row >> lg, yb = row & (S - 1);
  const int tid = threadIdx.x;
  const int xb = tid & (S - 1), cg = tid >> lg;
  const int NG = 256 >> lg;
  const int chpc = C / nch;
  const int cpt = chpc / NG;   // channels per thread

  const float* f1base = pr.x1[lvl] + (size_t)b * C * S * S + (size_t)yb * S + xb;
  const float* f2base = pr.x2[lvl] + (size_t)b * C * S * S;

  float acc[9];
#pragma unroll
  for (int j = 0; j < 9; ++j) acc[j] = 0.f;

  const int c0 = chunk * chpc + cg;
  for (int t = 0; t < cpt; ++t) {
    const int cc = c0 + t * NG;
    const float f1 = f1base[(size_t)cc * S * S];
    const float* p2 = f2base + (size_t)cc * S * S;
#pragma unroll
    for (int dy = 0; dy < 3; ++dy) {
      const int yy = yb + dy - 1;             // block-uniform branch
      if (yy < 0 || yy >= S) continue;
      const float* prow = p2 + yy * S;
#pragma unroll
      for (int dx = 0; dx < 3; ++dx) {
        const int xx = xb + dx - 1;
        const float v = (xx >= 0 && xx < S) ? prow[xx] : 0.f;
        acc[dy * 3 + dx] += f1 * v;
      }
    }
  }

  __shared__ float red[256 * 9];
#pragma unroll
  for (int j = 0; j < 9; ++j) red[tid * 9 + j] = acc[j];
  __syncthreads();
  for (int g = NG >> 1; g >= 1; g >>= 1) {
    if (cg < g) {
#pragma unroll
      for (int j = 0; j < 9; ++j) red[tid * 9 + j] += red[(tid + g * S) * 9 + j];
    }
    __syncthreads();
  }
  if (cg == 0) {
    float* Dp = pr.D[lvl] + ((size_t)(b * S + yb) * S + xb) * 9;
#pragma unroll
    for (int j = 0; j < 9; ++j) unsafeAtomicAdd(&Dp[j], red[tid * 9 + j]);
  }
}

// ---------------------------------------------------------------------------
// pool: pooled(b,p) = Wk * lrelu(corr(b,p)) * Wk^T via separable stencils.
// Wk[i][y] = ck[y - i*2^k] exactly for i>=1 (only row 0 clips at the pad);
// row 0 uses the left stencil cl. Both are built in-LDS in k<=6 steps.
// block = (b, p, yo-chunk); lrelu(D) rows staged in LDS.
// ---------------------------------------------------------------------------
__global__ __launch_bounds__(256) void pool_kernel(Params pr) {
  static const int SZt[6] = {64, 32, 16, 8, 4, 2};
  static const int NYC[6] = {8, 4, 2, 1, 1, 1};
  static const int LGS[6] = {6, 5, 4, 3, 2, 1};
  const int lvl = blockIdx.y;
  const int S = SZt[lvl], k = lvl + 1, f = 1 << k, nyc = NYC[lvl], lgS = LGS[lvl];
  const int nyo = S / nyc;
  const int bid = blockIdx.x;
  if (bid >= 50 * nyc) return;
  const int yc = bid / 50;
  const int bp = bid - yc * 50;
  const int b = bp / 25, p = bp - (bp / 25) * 25;
  const int dpy = p / 5 - 2, dpx = p - (p / 5) * 5 - 2;
  const int tid = threadIdx.x;
  const int yo0 = yc * nyo;

  __shared__ float ckb[2][130], clb[2][66];
  __shared__ float Dl[5184];        // (nyo+1)*S*9 <= 9*64*9
  __shared__ float tmp[1024];       // nyo*128 <= 8*128

  if (tid == 0) { ckb[0][0] = 1.f; clb[0][0] = 1.f; }
  __syncthreads();
  int rj = 0, cur = 0;
  for (int j = 0; j < k; ++j) {
    const int half = 1 << j, rn = 2 * half - 1;
    float cknew = 0.f, clnew = 0.f;
    if (tid <= 2 * rn) {
      const int t = tid - rn;
#pragma unroll
      for (int e = -1; e <= 1; ++e) {
        const int u = t + e * half;
        if (u >= -rj && u <= rj) cknew += ckb[cur][u + rj];
      }
      cknew *= (1.f / 3.f);
    }
    if (tid < 2 * half) {
      const int y = tid;
      float s = (y < half) ? clb[cur][y] : 0.f;
      const int u = y - half;
      if (u >= -rj && u <= rj) s += ckb[cur][u + rj];
      clnew = s * (1.f / 3.f);
    }
    __syncthreads();
    if (tid <= 2 * rn) ckb[cur ^ 1][tid] = cknew;
    if (tid < 2 * half) clb[cur ^ 1][tid] = clnew;
    __syncthreads();
    cur ^= 1;
    rj = rn;
  }
  const float* ck = ckb[cur];   // index t + (f-1)
  const float* cl = clb[cur];   // index y in [0, f)

  // stage lrelu(D) for yb in [yb0, yo0+nyo-1]
  const int yb0 = (yo0 > 0) ? yo0 - 1 : 0;
  const int nyb = (yo0 + nyo - 1) - yb0 + 1;
  const float* Dg = pr.D[lvl] + (size_t)b * S * S * 9 + (size_t)yb0 * S * 9;
  const int nload = nyb * S * 9;
  for (int i = tid; i < nload; i += 256) Dl[i] = lrelu(Dg[i]);
  __syncthreads();

  // phase 1: tmp[yol][x] = sum_y w(yo,y) * lrelu(corr(.., y, x))
  for (int item = tid; item < nyo * 128; item += 256) {
    const int yol = item >> 7, x = item & 127;
    const int yo = yo0 + yol;
    const int xb = x >> k, tx = x & (f - 1);
    const int txp = tx + dpx;
    const int dxi = (txp < 0) ? 0 : ((txp >= f) ? 2 : 1);
    float sum = 0.f;
    if (yo == 0) {
      for (int y = 0; y < f; ++y) {
        const int typ = y + dpy;     // yb = 0, ty = y
        const int dyi = (typ < 0) ? 0 : ((typ >= f) ? 2 : 1);
        sum += cl[y] * Dl[((0 - yb0) * S + xb) * 9 + dyi * 3 + dxi];
      }
    } else {
      const int ylo = yo * f - (f - 1);
      for (int t = 0; t < 2 * f - 1; ++t) {
        const int y = ylo + t;
        const int yb = y >> k, ty = y & (f - 1);
        const int typ = ty + dpy;
        const int dyi = (typ < 0) ? 0 : ((typ >= f) ? 2 : 1);
        sum += ck[t] * Dl[((yb - yb0) * S + xb) * 9 + dyi * 3 + dxi];
      }
    }
    tmp[yol * 128 + x] = sum;
  }
  __syncthreads();

  // phase 2: contract x
  float* out = pr.pooled[lvl] + (size_t)(b * PP + p) * S * S;
  for (int item = tid; item < nyo * S; item += 256) {
    const int yol = item >> lgS, xo = item & (S - 1);
    float sum = 0.f;
    if (xo == 0) {
      for (int x = 0; x < f; ++x) sum += cl[x] * tmp[yol * 128 + x];
    } else {
      const int xlo = xo * f - (f - 1);
      for (int t = 0; t < 2 * f - 1; ++t) sum += ck[t] * tmp[yol * 128 + xlo + t];
    }
    out[(size_t)(yo0 + yol) * S + xo] = sum;
  }
}

// ---------------------------------------------------------------------------
// conv: one gate-quadrant q per block (grid.z), one (b,y) row per block.x.
// Input rows staged padded in LDS so the 10-wide window is 3 aligned float4
// reads; weights from the repacked WT (lane-consecutive by oc).
// ---------------------------------------------------------------------------
__global__ __launch_bounds__(256) void conv_kernel(Params pr) {
  static const int SZt[6] = {64, 32, 16, 8, 4, 2};
  static const int LG[6]  = {6, 5, 4, 3, 2, 1};
  const int lvl = blockIdx.y;
  const int S = SZt[lvl], lg = LG[lvl];
  const int rows = NB * S;
  if ((int)blockIdx.x >= rows) return;
  const int b = blockIdx.x >> lg, y = blockIdx.x & (S - 1);
  const int q = blockIdx.z;
  const int tid = threadIdx.x;

  // LDS: [ky][ic][68], left pad 1, zero-padded edges
  __shared__ float in_lds[3 * 50 * 68];
  const float* pooled = pr.pooled[lvl] + (size_t)b * PP * S * S;
  const float* hin = pr.h[lvl] + (size_t)b * PP * S * S;
  for (int i = tid; i < 150 * 68; i += 256) {
    const int r = i / 68, xi = i - r * 68;
    const int ky = r / 50, ic = r - ky * 50;
    const int yy = y + ky - 1;
    const int x = xi - 1;
    float v = 0.f;
    if (yy >= 0 && yy < S && x >= 0 && x < S)
      v = (ic < PP) ? pooled[((size_t)ic * S + yy) * S + x]
                    : hin[((size_t)(ic - PP) * S + yy) * S + x];
    in_lds[i] = v;
  }
  __syncthreads();

  const int nxc = (S >= 8) ? (S >> 3) : 1;
  const int nitems = PP * nxc;
  if (tid >= nitems) return;
  const int xs = tid / 25;          // p fast-varying: weight loads coalesce
  const int p = tid - xs * 25;
  const int x0 = xs << 3;
  const int oc = q * PP + p;

  const float* WT = pr.WT[lvl];
  float acc[8];
#pragma unroll
  for (int xx = 0; xx < 8; ++xx) acc[xx] = 0.f;

  for (int ic = 0; ic < 50; ++ic) {
    const float* wrow = WT + (size_t)ic * 900 + oc;
#pragma unroll
    for (int ky = 0; ky < 3; ++ky) {
      const float w0 = wrow[(ky * 3 + 0) * 100];
      const float w1 = wrow[(ky * 3 + 1) * 100];
      const float w2 = wrow[(ky * 3 + 2) * 100];
      const float4* rp = (const float4*)&in_lds[(ky * 50 + ic) * 68];
      const int fi = x0 >> 2;
      const float4 A = rp[fi], Bv = rp[fi + 1], Cv = rp[fi + 2];
      const float sg[12] = {A.x, A.y, A.z, A.w, Bv.x, Bv.y, Bv.z, Bv.w,
                            Cv.x, Cv.y, Cv.z, Cv.w};
#pragma unroll
      for (int xx = 0; xx < 8; ++xx)
        acc[xx] = fmaf(w0, sg[xx], fmaf(w1, sg[xx + 1], fmaf(w2, sg[xx + 2], acc[xx])));
    }
  }

  const float bb = pr.bias[lvl][oc];
  float* g = pr.gates[lvl] + ((size_t)(q * NB + b) * PP + p) * S * S + (size_t)y * S + x0;
  if (S >= 8) {
    float4 o0, o1;
    o0.x = acc[0] + bb; o0.y = acc[1] + bb; o0.z = acc[2] + bb; o0.w = acc[3] + bb;
    o1.x = acc[4] + bb; o1.y = acc[5] + bb; o1.z = acc[6] + bb; o1.w = acc[7] + bb;
    ((float4*)g)[0] = o0;
    ((float4*)g)[1] = o1;
  } else {
#pragma unroll
    for (int xx = 0; xx < 8; ++xx)
      if (x0 + xx < S) g[xx] = acc[xx] + bb;
  }
}

// ---------------------------------------------------------------------------
// Pointwise LSTM: float4 over all sites of a level.
// ---------------------------------------------------------------------------
__global__ __launch_bounds__(256) void lstm_kernel(Params pr) {
  static const int SZt[6] = {64, 32, 16, 8, 4, 2};
  const int lvl = blockIdx.y;
  const int S = SZt[lvl];
  const int n4 = (NB * PP * S * S) >> 2;
  const int i4 = blockIdx.x * 256 + threadIdx.x;
  if (i4 >= n4) return;
  const float4* g0 = (const float4*)pr.gates[lvl];
  const float4 vi = g0[i4];
  const float4 vf = g0[n4 + i4];
  const float4 vo = g0[2 * n4 + i4];
  const float4 vg = g0[3 * n4 + i4];
  const float4 vc = ((const float4*)pr.c[lvl])[i4];
  float4 hn, cn;
  const float* gi = (const float*)&vi;
  const float* gf = (const float*)&vf;
  const float* go = (const float*)&vo;
  const float* gg = (const float*)&vg;
  const float* cp = (const float*)&vc;
  float* hp = (float*)&hn;
  float* cq = (float*)&cn;
#pragma unroll
  for (int j = 0; j < 4; ++j) {
    const float i_ = 1.f / (1.f + __expf(-gi[j]));
    const float f_ = 1.f / (1.f + __expf(-gf[j]));
    const float o_ = 1.f / (1.f + __expf(-go[j]));
    const float g_ = 1.f - 2.f / (__expf(2.f * gg[j]) + 1.f);
    const float c_ = f_ * cp[j] + i_ * g_;
    const float t2 = 1.f - 2.f / (__expf(2.f * c_) + 1.f);
    cq[j] = c_;
    hp[j] = o_ * t2;
  }
  ((float4*)pr.hout[lvl])[i4] = hn;
  ((float4*)pr.cout[lvl])[i4] = cn;
}

// ---------------------------------------------------------------------------
extern "C" void kernel_launch(void* const* d_in, const int* in_sizes, int n_in,
                              void* d_out, int out_size, void* d_ws, size_t ws_size,
                              hipStream_t stream) {
  static const int CH[NLVL] = {512, 1024, 512, 256, 256, 256};
  static const int SZ[NLVL] = {64, 32, 16, 8, 4, 2};

  Params pr;
  float* ws = (float*)d_ws;
  size_t off = 0;
  // D first (contiguous, one memset)
  const size_t Doff = off;
  for (int l = 0; l < NLVL; ++l) { pr.D[l] = ws + off; off += (size_t)NB * SZ[l] * SZ[l] * 9; }
  const size_t Dbytes = (off - Doff) * sizeof(float);
  for (int l = 0; l < NLVL; ++l) { pr.pooled[l] = ws + off; off += (size_t)NB * PP * SZ[l] * SZ[l]; }
  for (int l = 0; l < NLVL; ++l) { pr.WT[l] = ws + off; off += 100 * 450; }
  for (int l = 0; l < NLVL; ++l) { pr.gates[l] = ws + off; off += (size_t)4 * NB * PP * SZ[l] * SZ[l]; }

  float* out = (float*)d_out;
  size_t ooff = 0;
  for (int l = 0; l < NLVL; ++l) {
    pr.hout[l] = out + ooff; ooff += (size_t)NB * PP * SZ[l] * SZ[l];
    pr.cout[l] = out + ooff; ooff += (size_t)NB * PP * SZ[l] * SZ[l];
  }

  for (int l = 0; l < NLVL; ++l) {
    pr.x1[l] = (const float*)d_in[4 * l + 0];
    pr.x2[l] = (const float*)d_in[4 * l + 1];
    pr.h[l]  = (const float*)d_in[4 * l + 2];
    pr.c[l]  = (const float*)d_in[4 * l + 3];
    pr.W[l]    = (const float*)d_in[24 + 2 * l];
    pr.bias[l] = (const float*)d_in[25 + 2 * l];
  }

  hipMemsetAsync((void*)(ws + Doff), 0, Dbytes, stream);
  repack_kernel<<<dim3(45, NLVL), 256, 0, stream>>>(pr);
  dcorr_kernel<<<dim3(2048, NLVL), 256, 0, stream>>>(pr);
  pool_kernel<<<dim3(400, NLVL), 256, 0, stream>>>(pr);
  conv_kernel<<<dim3(128, NLVL, 4), 256, 0, stream>>>(pr);
  lstm_kernel<<<dim3(200, NLVL), 256, 0, stream>>>(pr);
}

// Round 3
// 274.300 us; speedup vs baseline: 1.2444x; 1.1197x over previous
//
#include <hip/hip_runtime.h>

#define NB 2      // batch
#define PP 25     // patch area (5x5)
#define NLVL 6

struct Params {
  const float* x1[NLVL];
  const float* x2[NLVL];
  const float* h[NLVL];
  const float* c[NLVL];
  const float* W[NLVL];
  const float* bias[NLVL];
  float* Dpart[NLVL];   // per-chunk partials, nch * B*S*S*9
  float* D[NLVL];       // lrelu(sum of partials), B*S*S*9
  float* pooled[NLVL];  // pooled corr, B*25*S*S
  float* WT[NLVL];      // repacked weights [(ic*9+t)*100 + oc]
  float* gates[NLVL];   // conv outputs, 4*NB*25*S*S
  float* hout[NLVL];
  float* cout[NLVL];
};

__device__ __forceinline__ float lrelu(float v) { return v > 0.f ? v : 0.01f * v; }

// ---------------------------------------------------------------------------
// Repack W[oc][ic][ky][kx] -> WT[(ic*9+t)][oc] so a wave's weight load is
// 25 consecutive floats (lane = p).
// ---------------------------------------------------------------------------
__global__ __launch_bounds__(256) void repack_kernel(Params pr) {
  const int lvl = blockIdx.y;
  const float* W = pr.W[lvl];
  float* WT = pr.WT[lvl];
  for (int i = blockIdx.x * 256 + threadIdx.x; i < 100 * 450; i += gridDim.x * 256) {
    const int oc = i / 450;
    const int r = i - oc * 450;   // r = ic*9 + (ky*3+kx)
    WT[r * 100 + oc] = W[i];
  }
}

// ---------------------------------------------------------------------------
// dcorr: partial[chunk][b,yb,xb,j] = sum_{c in chunk} f1[b,c,yb,xb]*f2[b,c,nbr_j]
// Fast path (S>=16): thread owns 4 consecutive xb via float4 loads, 2 channels
// unrolled -> ~20 independent loads in flight. No atomics: plain stores into
// a per-chunk slab; dreduce sums them.
// ---------------------------------------------------------------------------
__global__ __launch_bounds__(256) void dcorr_kernel(Params pr) {
  static const int SZt[6] = {64, 32, 16, 8, 4, 2};
  static const int CHt[6] = {512, 1024, 512, 256, 256, 256};
  static const int NCH[6] = {16, 16, 4, 1, 1, 1};
  static const int LGQ[6] = {4, 3, 2, 0, 0, 0};   // log2(S/4) for fast levels
  const int lvl = blockIdx.y;
  const int S = SZt[lvl], C = CHt[lvl], nch = NCH[lvl];
  const int rows = NB * S;
  const int bid = blockIdx.x;
  if (bid >= rows * nch) return;
  const int row = bid / nch;
  const int chunk = bid - row * nch;
  const int b = row / S, yb = row - b * S;
  const int tid = threadIdx.x;
  const size_t nlev = (size_t)NB * S * S * 9;
  float* part = pr.Dpart[lvl] + (size_t)chunk * nlev;

  __shared__ float red[9216];

  if (S >= 16) {
    const int lgq = LGQ[lvl];
    const int xqn = S >> 2;            // threads along x (float4 units)
    const int cgn = 256 >> lgq;        // channel groups
    const int xq = tid & (xqn - 1);
    const int cg = tid >> lgq;
    const int chpc = C / nch;
    const int cpt = chpc / cgn;        // channels per thread (=2)
    const int xb0 = xq << 2;

    const float* f1b = pr.x1[lvl] + (size_t)b * C * S * S + (size_t)yb * S + xb0;
    const float* f2b = pr.x2[lvl] + (size_t)b * C * S * S;

    float acc[9][4];
#pragma unroll
    for (int jj = 0; jj < 9; ++jj)
#pragma unroll
      for (int j = 0; j < 4; ++j) acc[jj][j] = 0.f;

    const int c0 = chunk * chpc + cg;
    for (int t = 0; t < cpt; ++t) {
      const int cc = c0 + t * cgn;
      const float4 f1 = *(const float4*)(f1b + (size_t)cc * S * S);
      const float f1a[4] = {f1.x, f1.y, f1.z, f1.w};
      const float* p2 = f2b + (size_t)cc * S * S;
#pragma unroll
      for (int dy = 0; dy < 3; ++dy) {
        const int yy = yb + dy - 1;               // block-uniform branch
        if (yy < 0 || yy >= S) continue;
        const float* prow = p2 + (size_t)yy * S;
        const float4 m = *(const float4*)(prow + xb0);
        const float lm = (xb0 > 0) ? prow[xb0 - 1] : 0.f;
        const float rm = (xb0 + 4 < S) ? prow[xb0 + 4] : 0.f;
        const float wl[4] = {lm, m.x, m.y, m.z};
        const float wc[4] = {m.x, m.y, m.z, m.w};
        const float wr[4] = {m.y, m.z, m.w, rm};
#pragma unroll
        for (int j = 0; j < 4; ++j) {
          acc[dy * 3 + 0][j] = fmaf(f1a[j], wl[j], acc[dy * 3 + 0][j]);
          acc[dy * 3 + 1][j] = fmaf(f1a[j], wc[j], acc[dy * 3 + 1][j]);
          acc[dy * 3 + 2][j] = fmaf(f1a[j], wr[j], acc[dy * 3 + 2][j]);
        }
      }
    }

    const int n = S * 9;
#pragma unroll
    for (int jj = 0; jj < 9; ++jj)
#pragma unroll
      for (int j = 0; j < 4; ++j)
        red[cg * n + (xb0 + j) * 9 + jj] = acc[jj][j];
    __syncthreads();
    for (int g = cgn >> 1; g >= 1; g >>= 1) {
      for (int i = tid; i < g * n; i += 256) {
        const int c = i / n, e = i - c * n;
        red[c * n + e] += red[(c + g) * n + e];
      }
      __syncthreads();
    }
    float* out = part + (size_t)(b * S + yb) * S * 9;
    for (int i = tid; i < n; i += 256) out[i] = red[i];
  } else {
    // small levels (S=8,4,2): scalar per-site path, nch==1
    const int lg = (S == 8) ? 3 : ((S == 4) ? 2 : 1);
    const int xb = tid & (S - 1), cg = tid >> lg;
    const int NG = 256 >> lg;
    const int cpt = C / NG;

    const float* f1base = pr.x1[lvl] + (size_t)b * C * S * S + (size_t)yb * S + xb;
    const float* f2base = pr.x2[lvl] + (size_t)b * C * S * S;

    float acc[9];
#pragma unroll
    for (int j = 0; j < 9; ++j) acc[j] = 0.f;

    for (int t = 0; t < cpt; ++t) {
      const int cc = cg + t * NG;
      const float f1 = f1base[(size_t)cc * S * S];
      const float* p2 = f2base + (size_t)cc * S * S;
#pragma unroll
      for (int dy = 0; dy < 3; ++dy) {
        const int yy = yb + dy - 1;
        if (yy < 0 || yy >= S) continue;
        const float* prow = p2 + yy * S;
#pragma unroll
        for (int dx = 0; dx < 3; ++dx) {
          const int xx = xb + dx - 1;
          const float v = (xx >= 0 && xx < S) ? prow[xx] : 0.f;
          acc[dy * 3 + dx] += f1 * v;
        }
      }
    }

#pragma unroll
    for (int j = 0; j < 9; ++j) red[tid * 9 + j] = acc[j];
    __syncthreads();
    for (int g = NG >> 1; g >= 1; g >>= 1) {
      if (cg < g) {
#pragma unroll
        for (int j = 0; j < 9; ++j) red[tid * 9 + j] += red[(tid + g * S) * 9 + j];
      }
      __syncthreads();
    }
    if (cg == 0) {
      float* Dp = part + ((size_t)(b * S + yb) * S + xb) * 9;
#pragma unroll
      for (int j = 0; j < 9; ++j) Dp[j] = red[tid * 9 + j];
    }
  }
}

// ---------------------------------------------------------------------------
// dreduce: D = lrelu(sum over chunks of Dpart). Pool consumes D directly.
// ---------------------------------------------------------------------------
__global__ __launch_bounds__(256) void dreduce_kernel(Params pr) {
  static const int SZt[6] = {64, 32, 16, 8, 4, 2};
  static const int NCH[6] = {16, 16, 4, 1, 1, 1};
  const int lvl = blockIdx.y;
  const int S = SZt[lvl], nch = NCH[lvl];
  const int n = NB * S * S * 9;
  const int i = blockIdx.x * 256 + threadIdx.x;
  if (i >= n) return;
  const float* part = pr.Dpart[lvl];
  float s = 0.f;
  for (int c = 0; c < nch; ++c) s += part[(size_t)c * n + i];
  pr.D[lvl][i] = lrelu(s);
}

// ---------------------------------------------------------------------------
// pool: pooled(b,p) = Wk * lreluD(b,p) * Wk^T via separable stencils.
// Wk[i][y] = ck[y - i*2^k] exactly for i>=1; row 0 uses the left stencil cl.
// ---------------------------------------------------------------------------
__global__ __launch_bounds__(256) void pool_kernel(Params pr) {
  static const int SZt[6] = {64, 32, 16, 8, 4, 2};
  static const int NYC[6] = {8, 4, 2, 1, 1, 1};
  static const int LGS[6] = {6, 5, 4, 3, 2, 1};
  const int lvl = blockIdx.y;
  const int S = SZt[lvl], k = lvl + 1, f = 1 << k, nyc = NYC[lvl], lgS = LGS[lvl];
  const int nyo = S / nyc;
  const int bid = blockIdx.x;
  if (bid >= 50 * nyc) return;
  const int yc = bid / 50;
  const int bp = bid - yc * 50;
  const int b = bp / 25, p = bp - (bp / 25) * 25;
  const int dpy = p / 5 - 2, dpx = p - (p / 5) * 5 - 2;
  const int tid = threadIdx.x;
  const int yo0 = yc * nyo;

  __shared__ float ckb[2][130], clb[2][66];
  __shared__ float Dl[5184];        // (nyo+1)*S*9 <= 9*64*9
  __shared__ float tmp[1024];       // nyo*128 <= 8*128

  if (tid == 0) { ckb[0][0] = 1.f; clb[0][0] = 1.f; }
  __syncthreads();
  int rj = 0, cur = 0;
  for (int j = 0; j < k; ++j) {
    const int half = 1 << j, rn = 2 * half - 1;
    float cknew = 0.f, clnew = 0.f;
    if (tid <= 2 * rn) {
      const int t = tid - rn;
#pragma unroll
      for (int e = -1; e <= 1; ++e) {
        const int u = t + e * half;
        if (u >= -rj && u <= rj) cknew += ckb[cur][u + rj];
      }
      cknew *= (1.f / 3.f);
    }
    if (tid < 2 * half) {
      const int y = tid;
      float s = (y < half) ? clb[cur][y] : 0.f;
      const int u = y - half;
      if (u >= -rj && u <= rj) s += ckb[cur][u + rj];
      clnew = s * (1.f / 3.f);
    }
    __syncthreads();
    if (tid <= 2 * rn) ckb[cur ^ 1][tid] = cknew;
    if (tid < 2 * half) clb[cur ^ 1][tid] = clnew;
    __syncthreads();
    cur ^= 1;
    rj = rn;
  }
  const float* ck = ckb[cur];   // index t + (f-1)
  const float* cl = clb[cur];   // index y in [0, f)

  // stage D rows yb in [yb0, yo0+nyo-1]
  const int yb0 = (yo0 > 0) ? yo0 - 1 : 0;
  const int nyb = (yo0 + nyo - 1) - yb0 + 1;
  const float* Dg = pr.D[lvl] + (size_t)b * S * S * 9 + (size_t)yb0 * S * 9;
  const int nload = nyb * S * 9;
  for (int i = tid; i < nload; i += 256) Dl[i] = Dg[i];
  __syncthreads();

  // phase 1: tmp[yol][x] = sum_y w(yo,y) * D(.., y, x)
  for (int item = tid; item < nyo * 128; item += 256) {
    const int yol = item >> 7, x = item & 127;
    const int yo = yo0 + yol;
    const int xb = x >> k, tx = x & (f - 1);
    const int txp = tx + dpx;
    const int dxi = (txp < 0) ? 0 : ((txp >= f) ? 2 : 1);
    float sum = 0.f;
    if (yo == 0) {
      for (int y = 0; y < f; ++y) {
        const int typ = y + dpy;     // yb = 0, ty = y
        const int dyi = (typ < 0) ? 0 : ((typ >= f) ? 2 : 1);
        sum += cl[y] * Dl[((0 - yb0) * S + xb) * 9 + dyi * 3 + dxi];
      }
    } else {
      const int ylo = yo * f - (f - 1);
      for (int t = 0; t < 2 * f - 1; ++t) {
        const int y = ylo + t;
        const int yb = y >> k, ty = y & (f - 1);
        const int typ = ty + dpy;
        const int dyi = (typ < 0) ? 0 : ((typ >= f) ? 2 : 1);
        sum += ck[t] * Dl[((yb - yb0) * S + xb) * 9 + dyi * 3 + dxi];
      }
    }
    tmp[yol * 128 + x] = sum;
  }
  __syncthreads();

  // phase 2: contract x
  float* out = pr.pooled[lvl] + (size_t)(b * PP + p) * S * S;
  for (int item = tid; item < nyo * S; item += 256) {
    const int yol = item >> lgS, xo = item & (S - 1);
    float sum = 0.f;
    if (xo == 0) {
      for (int x = 0; x < f; ++x) sum += cl[x] * tmp[yol * 128 + x];
    } else {
      const int xlo = xo * f - (f - 1);
      for (int t = 0; t < 2 * f - 1; ++t) sum += ck[t] * tmp[yol * 128 + xlo + t];
    }
    out[(size_t)(yo0 + yol) * S + xo] = sum;
  }
}

// ---------------------------------------------------------------------------
// conv: one gate-quadrant q per block (grid.z), one (b,y) row per block.x.
// ---------------------------------------------------------------------------
__global__ __launch_bounds__(256) void conv_kernel(Params pr) {
  static const int SZt[6] = {64, 32, 16, 8, 4, 2};
  static const int LG[6]  = {6, 5, 4, 3, 2, 1};
  const int lvl = blockIdx.y;
  const int S = SZt[lvl], lg = LG[lvl];
  const int rows = NB * S;
  if ((int)blockIdx.x >= rows) return;
  const int b = blockIdx.x >> lg, y = blockIdx.x & (S - 1);
  const int q = blockIdx.z;
  const int tid = threadIdx.x;

  __shared__ float in_lds[3 * 50 * 68];
  const float* pooled = pr.pooled[lvl] + (size_t)b * PP * S * S;
  const float* hin = pr.h[lvl] + (size_t)b * PP * S * S;
  for (int i = tid; i < 150 * 68; i += 256) {
    const int r = i / 68, xi = i - r * 68;
    const int ky = r / 50, ic = r - ky * 50;
    const int yy = y + ky - 1;
    const int x = xi - 1;
    float v = 0.f;
    if (yy >= 0 && yy < S && x >= 0 && x < S)
      v = (ic < PP) ? pooled[((size_t)ic * S + yy) * S + x]
                    : hin[((size_t)(ic - PP) * S + yy) * S + x];
    in_lds[i] = v;
  }
  __syncthreads();

  const int nxc = (S >= 8) ? (S >> 3) : 1;
  const int nitems = PP * nxc;
  if (tid >= nitems) return;
  const int xs = tid / 25;          // p fast-varying: weight loads coalesce
  const int p = tid - xs * 25;
  const int x0 = xs << 3;
  const int oc = q * PP + p;

  const float* WT = pr.WT[lvl];
  float acc[8];
#pragma unroll
  for (int xx = 0; xx < 8; ++xx) acc[xx] = 0.f;

  for (int ic = 0; ic < 50; ++ic) {
    const float* wrow = WT + (size_t)ic * 900 + oc;
#pragma unroll
    for (int ky = 0; ky < 3; ++ky) {
      const float w0 = wrow[(ky * 3 + 0) * 100];
      const float w1 = wrow[(ky * 3 + 1) * 100];
      const float w2 = wrow[(ky * 3 + 2) * 100];
      const float4* rp = (const float4*)&in_lds[(ky * 50 + ic) * 68];
      const int fi = x0 >> 2;
      const float4 A = rp[fi], Bv = rp[fi + 1], Cv = rp[fi + 2];
      const float sg[12] = {A.x, A.y, A.z, A.w, Bv.x, Bv.y, Bv.z, Bv.w,
                            Cv.x, Cv.y, Cv.z, Cv.w};
#pragma unroll
      for (int xx = 0; xx < 8; ++xx)
        acc[xx] = fmaf(w0, sg[xx], fmaf(w1, sg[xx + 1], fmaf(w2, sg[xx + 2], acc[xx])));
    }
  }

  const float bb = pr.bias[lvl][oc];
  float* g = pr.gates[lvl] + ((size_t)(q * NB + b) * PP + p) * S * S + (size_t)y * S + x0;
  if (S >= 8) {
    float4 o0, o1;
    o0.x = acc[0] + bb; o0.y = acc[1] + bb; o0.z = acc[2] + bb; o0.w = acc[3] + bb;
    o1.x = acc[4] + bb; o1.y = acc[5] + bb; o1.z = acc[6] + bb; o1.w = acc[7] + bb;
    ((float4*)g)[0] = o0;
    ((float4*)g)[1] = o1;
  } else {
#pragma unroll
    for (int xx = 0; xx < 8; ++xx)
      if (x0 + xx < S) g[xx] = acc[xx] + bb;
  }
}

// ---------------------------------------------------------------------------
// Pointwise LSTM: float4 over all sites of a level.
// ---------------------------------------------------------------------------
__global__ __launch_bounds__(256) void lstm_kernel(Params pr) {
  static const int SZt[6] = {64, 32, 16, 8, 4, 2};
  const int lvl = blockIdx.y;
  const int S = SZt[lvl];
  const int n4 = (NB * PP * S * S) >> 2;
  const int i4 = blockIdx.x * 256 + threadIdx.x;
  if (i4 >= n4) return;
  const float4* g0 = (const float4*)pr.gates[lvl];
  const float4 vi = g0[i4];
  const float4 vf = g0[n4 + i4];
  const float4 vo = g0[2 * n4 + i4];
  const float4 vg = g0[3 * n4 + i4];
  const float4 vc = ((const float4*)pr.c[lvl])[i4];
  float4 hn, cn;
  const float* gi = (const float*)&vi;
  const float* gf = (const float*)&vf;
  const float* go = (const float*)&vo;
  const float* gg = (const float*)&vg;
  const float* cp = (const float*)&vc;
  float* hp = (float*)&hn;
  float* cq = (float*)&cn;
#pragma unroll
  for (int j = 0; j < 4; ++j) {
    const float i_ = 1.f / (1.f + __expf(-gi[j]));
    const float f_ = 1.f / (1.f + __expf(-gf[j]));
    const float o_ = 1.f / (1.f + __expf(-go[j]));
    const float g_ = 1.f - 2.f / (__expf(2.f * gg[j]) + 1.f);
    const float c_ = f_ * cp[j] + i_ * g_;
    const float t2 = 1.f - 2.f / (__expf(2.f * c_) + 1.f);
    cq[j] = c_;
    hp[j] = o_ * t2;
  }
  ((float4*)pr.hout[lvl])[i4] = hn;
  ((float4*)pr.cout[lvl])[i4] = cn;
}

// ---------------------------------------------------------------------------
extern "C" void kernel_launch(void* const* d_in, const int* in_sizes, int n_in,
                              void* d_out, int out_size, void* d_ws, size_t ws_size,
                              hipStream_t stream) {
  static const int SZ[NLVL] = {64, 32, 16, 8, 4, 2};
  static const int NCH[NLVL] = {16, 16, 4, 1, 1, 1};

  Params pr;
  float* ws = (float*)d_ws;
  size_t off = 0;
  for (int l = 0; l < NLVL; ++l) {
    pr.Dpart[l] = ws + off;
    off += (size_t)NCH[l] * NB * SZ[l] * SZ[l] * 9;
  }
  for (int l = 0; l < NLVL; ++l) { pr.D[l] = ws + off; off += (size_t)NB * SZ[l] * SZ[l] * 9; }
  for (int l = 0; l < NLVL; ++l) { pr.pooled[l] = ws + off; off += (size_t)NB * PP * SZ[l] * SZ[l]; }
  for (int l = 0; l < NLVL; ++l) { pr.WT[l] = ws + off; off += 100 * 450; }
  for (int l = 0; l < NLVL; ++l) { pr.gates[l] = ws + off; off += (size_t)4 * NB * PP * SZ[l] * SZ[l]; }

  float* out = (float*)d_out;
  size_t ooff = 0;
  for (int l = 0; l < NLVL; ++l) {
    pr.hout[l] = out + ooff; ooff += (size_t)NB * PP * SZ[l] * SZ[l];
    pr.cout[l] = out + ooff; ooff += (size_t)NB * PP * SZ[l] * SZ[l];
  }

  for (int l = 0; l < NLVL; ++l) {
    pr.x1[l] = (const float*)d_in[4 * l + 0];
    pr.x2[l] = (const float*)d_in[4 * l + 1];
    pr.h[l]  = (const float*)d_in[4 * l + 2];
    pr.c[l]  = (const float*)d_in[4 * l + 3];
    pr.W[l]    = (const float*)d_in[24 + 2 * l];
    pr.bias[l] = (const float*)d_in[25 + 2 * l];
  }

  repack_kernel<<<dim3(45, NLVL), 256, 0, stream>>>(pr);
  dcorr_kernel<<<dim3(2048, NLVL), 256, 0, stream>>>(pr);
  dreduce_kernel<<<dim3(288, NLVL), 256, 0, stream>>>(pr);
  pool_kernel<<<dim3(400, NLVL), 256, 0, stream>>>(pr);
  conv_kernel<<<dim3(128, NLVL, 4), 256, 0, stream>>>(pr);
  lstm_kernel<<<dim3(200, NLVL), 256, 0, stream>>>(pr);
}

// Round 4
// 269.217 us; speedup vs baseline: 1.2679x; 1.0189x over previous
//
#include <hip/hip_runtime.h>

#define NB 2      // batch
#define PP 25     // patch area (5x5)
#define NLVL 6

struct Params {
  const float* x1[NLVL];
  const float* x2[NLVL];
  const float* h[NLVL];
  const float* c[NLVL];
  const float* W[NLVL];
  const float* bias[NLVL];
  float* Dpart[NLVL];   // per-chunk partials, nch * B*S*S*9
  float* D[NLVL];       // lrelu(sum of partials), B*S*S*9
  float* pooled[NLVL];  // pooled corr, B*25*S*S
  float* WT[NLVL];      // repacked weights [(ic*9+t)*100 + oc]
  float* gates[NLVL];   // conv outputs, 4*NB*25*S*S
  float* hout[NLVL];
  float* cout[NLVL];
};

__device__ __forceinline__ float lrelu(float v) { return v > 0.f ? v : 0.01f * v; }

// ---------------------------------------------------------------------------
// Repack W[oc][ic][ky][kx] -> WT[(ic*9+t)][oc] so a wave's weight load is
// 25 consecutive floats (lane = p).
// ---------------------------------------------------------------------------
__global__ __launch_bounds__(256) void repack_kernel(Params pr) {
  const int lvl = blockIdx.y;
  const float* W = pr.W[lvl];
  float* WT = pr.WT[lvl];
  for (int i = blockIdx.x * 256 + threadIdx.x; i < 100 * 450; i += gridDim.x * 256) {
    const int oc = i / 450;
    const int r = i - oc * 450;   // r = ic*9 + (ky*3+kx)
    WT[r * 100 + oc] = W[i];
  }
}

// ---------------------------------------------------------------------------
// dcorr: partial[chunk][b,yb,xb,j] = sum_{c in chunk} f1[b,c,yb,xb]*f2[b,c,nbr_j]
// ---------------------------------------------------------------------------
__global__ __launch_bounds__(256) void dcorr_kernel(Params pr) {
  static const int SZt[6] = {64, 32, 16, 8, 4, 2};
  static const int CHt[6] = {512, 1024, 512, 256, 256, 256};
  static const int NCH[6] = {16, 16, 4, 1, 1, 1};
  static const int LGQ[6] = {4, 3, 2, 0, 0, 0};   // log2(S/4) for fast levels
  const int lvl = blockIdx.y;
  const int S = SZt[lvl], C = CHt[lvl], nch = NCH[lvl];
  const int rows = NB * S;
  const int bid = blockIdx.x;
  if (bid >= rows * nch) return;
  const int row = bid / nch;
  const int chunk = bid - row * nch;
  const int b = row / S, yb = row - b * S;
  const int tid = threadIdx.x;
  const size_t nlev = (size_t)NB * S * S * 9;
  float* part = pr.Dpart[lvl] + (size_t)chunk * nlev;

  __shared__ float red[9216];

  if (S >= 16) {
    const int lgq = LGQ[lvl];
    const int xqn = S >> 2;            // threads along x (float4 units)
    const int cgn = 256 >> lgq;        // channel groups
    const int xq = tid & (xqn - 1);
    const int cg = tid >> lgq;
    const int chpc = C / nch;
    const int cpt = chpc / cgn;        // channels per thread (=2)
    const int xb0 = xq << 2;

    const float* f1b = pr.x1[lvl] + (size_t)b * C * S * S + (size_t)yb * S + xb0;
    const float* f2b = pr.x2[lvl] + (size_t)b * C * S * S;

    float acc[9][4];
#pragma unroll
    for (int jj = 0; jj < 9; ++jj)
#pragma unroll
      for (int j = 0; j < 4; ++j) acc[jj][j] = 0.f;

    const int c0 = chunk * chpc + cg;
    for (int t = 0; t < cpt; ++t) {
      const int cc = c0 + t * cgn;
      const float4 f1 = *(const float4*)(f1b + (size_t)cc * S * S);
      const float f1a[4] = {f1.x, f1.y, f1.z, f1.w};
      const float* p2 = f2b + (size_t)cc * S * S;
#pragma unroll
      for (int dy = 0; dy < 3; ++dy) {
        const int yy = yb + dy - 1;               // block-uniform branch
        if (yy < 0 || yy >= S) continue;
        const float* prow = p2 + (size_t)yy * S;
        const float4 m = *(const float4*)(prow + xb0);
        const float lm = (xb0 > 0) ? prow[xb0 - 1] : 0.f;
        const float rm = (xb0 + 4 < S) ? prow[xb0 + 4] : 0.f;
        const float wl[4] = {lm, m.x, m.y, m.z};
        const float wc[4] = {m.x, m.y, m.z, m.w};
        const float wr[4] = {m.y, m.z, m.w, rm};
#pragma unroll
        for (int j = 0; j < 4; ++j) {
          acc[dy * 3 + 0][j] = fmaf(f1a[j], wl[j], acc[dy * 3 + 0][j]);
          acc[dy * 3 + 1][j] = fmaf(f1a[j], wc[j], acc[dy * 3 + 1][j]);
          acc[dy * 3 + 2][j] = fmaf(f1a[j], wr[j], acc[dy * 3 + 2][j]);
        }
      }
    }

    const int n = S * 9;
#pragma unroll
    for (int jj = 0; jj < 9; ++jj)
#pragma unroll
      for (int j = 0; j < 4; ++j)
        red[cg * n + (xb0 + j) * 9 + jj] = acc[jj][j];
    __syncthreads();
    for (int g = cgn >> 1; g >= 1; g >>= 1) {
      for (int i = tid; i < g * n; i += 256) {
        const int c = i / n, e = i - c * n;
        red[c * n + e] += red[(c + g) * n + e];
      }
      __syncthreads();
    }
    float* out = part + (size_t)(b * S + yb) * S * 9;
    for (int i = tid; i < n; i += 256) out[i] = red[i];
  } else {
    // small levels (S=8,4,2): scalar per-site path, nch==1
    const int lg = (S == 8) ? 3 : ((S == 4) ? 2 : 1);
    const int xb = tid & (S - 1), cg = tid >> lg;
    const int NG = 256 >> lg;
    const int cpt = C / NG;

    const float* f1base = pr.x1[lvl] + (size_t)b * C * S * S + (size_t)yb * S + xb;
    const float* f2base = pr.x2[lvl] + (size_t)b * C * S * S;

    float acc[9];
#pragma unroll
    for (int j = 0; j < 9; ++j) acc[j] = 0.f;

    for (int t = 0; t < cpt; ++t) {
      const int cc = cg + t * NG;
      const float f1 = f1base[(size_t)cc * S * S];
      const float* p2 = f2base + (size_t)cc * S * S;
#pragma unroll
      for (int dy = 0; dy < 3; ++dy) {
        const int yy = yb + dy - 1;
        if (yy < 0 || yy >= S) continue;
        const float* prow = p2 + yy * S;
#pragma unroll
        for (int dx = 0; dx < 3; ++dx) {
          const int xx = xb + dx - 1;
          const float v = (xx >= 0 && xx < S) ? prow[xx] : 0.f;
          acc[dy * 3 + dx] += f1 * v;
        }
      }
    }

#pragma unroll
    for (int j = 0; j < 9; ++j) red[tid * 9 + j] = acc[j];
    __syncthreads();
    for (int g = NG >> 1; g >= 1; g >>= 1) {
      if (cg < g) {
#pragma unroll
        for (int j = 0; j < 9; ++j) red[tid * 9 + j] += red[(tid + g * S) * 9 + j];
      }
      __syncthreads();
    }
    if (cg == 0) {
      float* Dp = part + ((size_t)(b * S + yb) * S + xb) * 9;
#pragma unroll
      for (int j = 0; j < 9; ++j) Dp[j] = red[tid * 9 + j];
    }
  }
}

// ---------------------------------------------------------------------------
// dreduce: D = lrelu(sum over chunks of Dpart).
// ---------------------------------------------------------------------------
__global__ __launch_bounds__(256) void dreduce_kernel(Params pr) {
  static const int SZt[6] = {64, 32, 16, 8, 4, 2};
  static const int NCH[6] = {16, 16, 4, 1, 1, 1};
  const int lvl = blockIdx.y;
  const int S = SZt[lvl], nch = NCH[lvl];
  const int n = NB * S * S * 9;
  const int i = blockIdx.x * 256 + threadIdx.x;
  if (i >= n) return;
  const float* part = pr.Dpart[lvl];
  float s = 0.f;
  for (int c = 0; c < nch; ++c) s += part[(size_t)c * n + i];
  pr.D[lvl][i] = lrelu(s);
}

// ---------------------------------------------------------------------------
// pool: pooled(b,p) = Wk * lreluD(b,p) * Wk^T via separable stencils.
// ---------------------------------------------------------------------------
__global__ __launch_bounds__(256) void pool_kernel(Params pr) {
  static const int SZt[6] = {64, 32, 16, 8, 4, 2};
  static const int NYC[6] = {8, 4, 2, 1, 1, 1};
  static const int LGS[6] = {6, 5, 4, 3, 2, 1};
  const int lvl = blockIdx.y;
  const int S = SZt[lvl], k = lvl + 1, f = 1 << k, nyc = NYC[lvl], lgS = LGS[lvl];
  const int nyo = S / nyc;
  const int bid = blockIdx.x;
  if (bid >= 50 * nyc) return;
  const int yc = bid / 50;
  const int bp = bid - yc * 50;
  const int b = bp / 25, p = bp - (bp / 25) * 25;
  const int dpy = p / 5 - 2, dpx = p - (p / 5) * 5 - 2;
  const int tid = threadIdx.x;
  const int yo0 = yc * nyo;

  __shared__ float ckb[2][130], clb[2][66];
  __shared__ float Dl[5184];
  __shared__ float tmp[1024];

  if (tid == 0) { ckb[0][0] = 1.f; clb[0][0] = 1.f; }
  __syncthreads();
  int rj = 0, cur = 0;
  for (int j = 0; j < k; ++j) {
    const int half = 1 << j, rn = 2 * half - 1;
    float cknew = 0.f, clnew = 0.f;
    if (tid <= 2 * rn) {
      const int t = tid - rn;
#pragma unroll
      for (int e = -1; e <= 1; ++e) {
        const int u = t + e * half;
        if (u >= -rj && u <= rj) cknew += ckb[cur][u + rj];
      }
      cknew *= (1.f / 3.f);
    }
    if (tid < 2 * half) {
      const int y = tid;
      float s = (y < half) ? clb[cur][y] : 0.f;
      const int u = y - half;
      if (u >= -rj && u <= rj) s += ckb[cur][u + rj];
      clnew = s * (1.f / 3.f);
    }
    __syncthreads();
    if (tid <= 2 * rn) ckb[cur ^ 1][tid] = cknew;
    if (tid < 2 * half) clb[cur ^ 1][tid] = clnew;
    __syncthreads();
    cur ^= 1;
    rj = rn;
  }
  const float* ck = ckb[cur];   // index t + (f-1)
  const float* cl = clb[cur];   // index y in [0, f)

  const int yb0 = (yo0 > 0) ? yo0 - 1 : 0;
  const int nyb = (yo0 + nyo - 1) - yb0 + 1;
  const float* Dg = pr.D[lvl] + (size_t)b * S * S * 9 + (size_t)yb0 * S * 9;
  const int nload = nyb * S * 9;
  for (int i = tid; i < nload; i += 256) Dl[i] = Dg[i];
  __syncthreads();

  for (int item = tid; item < nyo * 128; item += 256) {
    const int yol = item >> 7, x = item & 127;
    const int yo = yo0 + yol;
    const int xb = x >> k, tx = x & (f - 1);
    const int txp = tx + dpx;
    const int dxi = (txp < 0) ? 0 : ((txp >= f) ? 2 : 1);
    float sum = 0.f;
    if (yo == 0) {
      for (int y = 0; y < f; ++y) {
        const int typ = y + dpy;
        const int dyi = (typ < 0) ? 0 : ((typ >= f) ? 2 : 1);
        sum += cl[y] * Dl[((0 - yb0) * S + xb) * 9 + dyi * 3 + dxi];
      }
    } else {
      const int ylo = yo * f - (f - 1);
      for (int t = 0; t < 2 * f - 1; ++t) {
        const int y = ylo + t;
        const int yb = y >> k, ty = y & (f - 1);
        const int typ = ty + dpy;
        const int dyi = (typ < 0) ? 0 : ((typ >= f) ? 2 : 1);
        sum += ck[t] * Dl[((yb - yb0) * S + xb) * 9 + dyi * 3 + dxi];
      }
    }
    tmp[yol * 128 + x] = sum;
  }
  __syncthreads();

  float* out = pr.pooled[lvl] + (size_t)(b * PP + p) * S * S;
  for (int item = tid; item < nyo * S; item += 256) {
    const int yol = item >> lgS, xo = item & (S - 1);
    float sum = 0.f;
    if (xo == 0) {
      for (int x = 0; x < f; ++x) sum += cl[x] * tmp[yol * 128 + x];
    } else {
      const int xlo = xo * f - (f - 1);
      for (int t = 0; t < 2 * f - 1; ++t) sum += ck[t] * tmp[yol * 128 + xlo + t];
    }
    out[(size_t)(yo0 + yol) * S + xo] = sum;
  }
}

// ---------------------------------------------------------------------------
// conv: q-quadrant per grid.z, (b, y, x-tile) per grid.x; 128-thread blocks.
// Inputs staged in LDS (xtile+halo wide); weights register-double-buffered
// (prefetch ic+1's 9 coalesced scalars during ic's 72 FMAs).
// ---------------------------------------------------------------------------
__global__ __launch_bounds__(128) void conv_kernel(Params pr) {
  static const int SZt[6] = {64, 32, 16, 8, 4, 2};
  static const int XT[6]  = {32, 32, 16, 8, 4, 2};   // x-tile
  static const int WD[6]  = {36, 36, 20, 12, 8, 8};  // staged width (mult of 4)
  const int lvl = blockIdx.y;
  const int S = SZt[lvl], xtile = XT[lvl], width = WD[lvl];
  const int ntx = S / xtile;            // 2 for lvl0, else 1
  const int nblk = NB * S * ntx;
  const int bid = blockIdx.x;
  if (bid >= nblk) return;
  const int b = bid / (S * ntx);
  const int rem = bid - b * (S * ntx);
  const int y = rem / ntx;
  const int xt = rem - y * ntx;
  const int x0 = xt * xtile;
  const int q = blockIdx.z;
  const int tid = threadIdx.x;

  __shared__ float in_lds[3 * 50 * 36 + 8];
  const float* pooled = pr.pooled[lvl] + (size_t)b * PP * S * S;
  const float* hin = pr.h[lvl] + (size_t)b * PP * S * S;
  {
    int i = tid;
    int r = i / width;
    int j = i - r * width;
    while (r < 150) {
      const int ky = r / 50;
      const int ic = r - ky * 50;
      const int yy = y + ky - 1;
      const int x = x0 + j - 1;
      float v = 0.f;
      if (yy >= 0 && yy < S && x >= 0 && x < S)
        v = (ic < PP) ? pooled[((size_t)ic * S + yy) * S + x]
                      : hin[((size_t)(ic - PP) * S + yy) * S + x];
      in_lds[r * width + j] = v;
      j += 128;
      while (j >= width) { j -= width; ++r; }
    }
  }
  __syncthreads();

  const int XC = (xtile >= 8) ? 8 : xtile;
  const int nxc = xtile / XC;
  const int nitems = PP * nxc;
  if (tid >= nitems) return;
  const int xs = tid / 25;
  const int p = tid - xs * 25;
  const int oc = q * PP + p;
  const float* wp = pr.WT[lvl] + oc;

  float w[9], wn[9];
#pragma unroll
  for (int t = 0; t < 9; ++t) w[t] = wp[t * 100];

  float acc[8];
#pragma unroll
  for (int xx = 0; xx < 8; ++xx) acc[xx] = 0.f;

  const int xoff = xs * XC;
  for (int ic = 0; ic < 50; ++ic) {
    if (ic < 49) {
      const float* wq = wp + (size_t)(ic + 1) * 900;
#pragma unroll
      for (int t = 0; t < 9; ++t) wn[t] = wq[t * 100];
    }
#pragma unroll
    for (int ky = 0; ky < 3; ++ky) {
      const float* row = &in_lds[(ky * 50 + ic) * width + xoff];
      const float4 A = ((const float4*)row)[0];
      const float4 Bv = ((const float4*)row)[1];
      const float4 Cv = ((const float4*)row)[2];
      const float sg[12] = {A.x, A.y, A.z, A.w, Bv.x, Bv.y, Bv.z, Bv.w,
                            Cv.x, Cv.y, Cv.z, Cv.w};
      const float w0 = w[ky * 3], w1 = w[ky * 3 + 1], w2 = w[ky * 3 + 2];
#pragma unroll
      for (int xx = 0; xx < 8; ++xx)
        acc[xx] = fmaf(w0, sg[xx], fmaf(w1, sg[xx + 1], fmaf(w2, sg[xx + 2], acc[xx])));
    }
#pragma unroll
    for (int t = 0; t < 9; ++t) w[t] = wn[t];
  }

  const float bb = pr.bias[lvl][oc];
  float* g = pr.gates[lvl] + ((size_t)(q * NB + b) * PP + p) * S * S +
             (size_t)y * S + x0 + xoff;
  if (XC == 8) {
    ((float4*)g)[0] = make_float4(acc[0] + bb, acc[1] + bb, acc[2] + bb, acc[3] + bb);
    ((float4*)g)[1] = make_float4(acc[4] + bb, acc[5] + bb, acc[6] + bb, acc[7] + bb);
  } else if (XC == 4) {
    ((float4*)g)[0] = make_float4(acc[0] + bb, acc[1] + bb, acc[2] + bb, acc[3] + bb);
  } else {
    g[0] = acc[0] + bb;
    g[1] = acc[1] + bb;
  }
}

// ---------------------------------------------------------------------------
// Pointwise LSTM: float4 over all sites of a level.
// ---------------------------------------------------------------------------
__global__ __launch_bounds__(256) void lstm_kernel(Params pr) {
  static const int SZt[6] = {64, 32, 16, 8, 4, 2};
  const int lvl = blockIdx.y;
  const int S = SZt[lvl];
  const int n4 = (NB * PP * S * S) >> 2;
  const int i4 = blockIdx.x * 256 + threadIdx.x;
  if (i4 >= n4) return;
  const float4* g0 = (const float4*)pr.gates[lvl];
  const float4 vi = g0[i4];
  const float4 vf = g0[n4 + i4];
  const float4 vo = g0[2 * n4 + i4];
  const float4 vg = g0[3 * n4 + i4];
  const float4 vc = ((const float4*)pr.c[lvl])[i4];
  float4 hn, cn;
  const float* gi = (const float*)&vi;
  const float* gf = (const float*)&vf;
  const float* go = (const float*)&vo;
  const float* gg = (const float*)&vg;
  const float* cp = (const float*)&vc;
  float* hp = (float*)&hn;
  float* cq = (float*)&cn;
#pragma unroll
  for (int j = 0; j < 4; ++j) {
    const float i_ = 1.f / (1.f + __expf(-gi[j]));
    const float f_ = 1.f / (1.f + __expf(-gf[j]));
    const float o_ = 1.f / (1.f + __expf(-go[j]));
    const float g_ = 1.f - 2.f / (__expf(2.f * gg[j]) + 1.f);
    const float c_ = f_ * cp[j] + i_ * g_;
    const float t2 = 1.f - 2.f / (__expf(2.f * c_) + 1.f);
    cq[j] = c_;
    hp[j] = o_ * t2;
  }
  ((float4*)pr.hout[lvl])[i4] = hn;
  ((float4*)pr.cout[lvl])[i4] = cn;
}

// ---------------------------------------------------------------------------
extern "C" void kernel_launch(void* const* d_in, const int* in_sizes, int n_in,
                              void* d_out, int out_size, void* d_ws, size_t ws_size,
                              hipStream_t stream) {
  static const int SZ[NLVL] = {64, 32, 16, 8, 4, 2};
  static const int NCH[NLVL] = {16, 16, 4, 1, 1, 1};

  Params pr;
  float* ws = (float*)d_ws;
  size_t off = 0;
  for (int l = 0; l < NLVL; ++l) {
    pr.Dpart[l] = ws + off;
    off += (size_t)NCH[l] * NB * SZ[l] * SZ[l] * 9;
  }
  for (int l = 0; l < NLVL; ++l) { pr.D[l] = ws + off; off += (size_t)NB * SZ[l] * SZ[l] * 9; }
  for (int l = 0; l < NLVL; ++l) { pr.pooled[l] = ws + off; off += (size_t)NB * PP * SZ[l] * SZ[l]; }
  for (int l = 0; l < NLVL; ++l) { pr.WT[l] = ws + off; off += 100 * 450; }
  for (int l = 0; l < NLVL; ++l) { pr.gates[l] = ws + off; off += (size_t)4 * NB * PP * SZ[l] * SZ[l]; }

  float* out = (float*)d_out;
  size_t ooff = 0;
  for (int l = 0; l < NLVL; ++l) {
    pr.hout[l] = out + ooff; ooff += (size_t)NB * PP * SZ[l] * SZ[l];
    pr.cout[l] = out + ooff; ooff += (size_t)NB * PP * SZ[l] * SZ[l];
  }

  for (int l = 0; l < NLVL; ++l) {
    pr.x1[l] = (const float*)d_in[4 * l + 0];
    pr.x2[l] = (const float*)d_in[4 * l + 1];
    pr.h[l]  = (const float*)d_in[4 * l + 2];
    pr.c[l]  = (const float*)d_in[4 * l + 3];
    pr.W[l]    = (const float*)d_in[24 + 2 * l];
    pr.bias[l] = (const float*)d_in[25 + 2 * l];
  }

  repack_kernel<<<dim3(45, NLVL), 256, 0, stream>>>(pr);
  dcorr_kernel<<<dim3(2048, NLVL), 256, 0, stream>>>(pr);
  dreduce_kernel<<<dim3(288, NLVL), 256, 0, stream>>>(pr);
  pool_kernel<<<dim3(400, NLVL), 256, 0, stream>>>(pr);
  conv_kernel<<<dim3(256, NLVL, 4), 128, 0, stream>>>(pr);
  lstm_kernel<<<dim3(200, NLVL), 256, 0, stream>>>(pr);
}